// Round 1
// baseline (1143.489 us; speedup 1.0000x reference)
//
#include <hip/hip_runtime.h>

typedef __attribute__((ext_vector_type(8))) short short8;
typedef __attribute__((ext_vector_type(4))) float f32x4;

#define T_TOK  131072
#define DMODEL 256
#define DHID   512
#define NEXP   8

// ---------------- ws layout (bytes) ----------------
// xb        : 0          size 67108864   (T*256 bf16)
// w1b       : 67108864   size 2097152
// w2b       : 69206016   size 2097152
// tok_list  : 71303168   size 4194304    (E*T int)
// wt_list   : 75497472   size 4194304    (E*T float)
// pack      : 79691776   size 524288     (T int)
// tkw       : 80216064   size 1048576    (T float2)
// part_cnt  : 81264640   size 262144     (8192*8 int)
// part_psum : 81526784   size 262144
// block_off : 81788928   size 262144
// cnt_total : 82051072   size 32
// total ~82 MB

__device__ __forceinline__ unsigned short f2bf(float f) {
  unsigned int u = __float_as_uint(f);
  u = (u + 0x7FFFu + ((u >> 16) & 1u)) >> 16;
  return (unsigned short)u;
}

// ---------------- weight fp32 -> bf16 ----------------
__global__ void k_wconv(const float* __restrict__ w1, const float* __restrict__ w2,
                        unsigned short* __restrict__ w1b, unsigned short* __restrict__ w2b) {
  int i = blockIdx.x * 256 + threadIdx.x;  // 262144 threads, one float4 per array each
  float4 a = ((const float4*)w1)[i];
  ushort4 ua; ua.x = f2bf(a.x); ua.y = f2bf(a.y); ua.z = f2bf(a.z); ua.w = f2bf(a.w);
  ((ushort4*)w1b)[i] = ua;
  float4 b = ((const float4*)w2)[i];
  ushort4 ub; ub.x = f2bf(b.x); ub.y = f2bf(b.y); ub.z = f2bf(b.z); ub.w = f2bf(b.w);
  ((ushort4*)w2b)[i] = ub;
}

// ---------------- router: fp64 logits, top-2, x->bf16, per-block hist ----------------
__global__ __launch_bounds__(256) void k_router(
    const float* __restrict__ x, const float* __restrict__ gate,
    unsigned short* __restrict__ xb, int* __restrict__ pack, float2* __restrict__ tkw,
    int* __restrict__ part_cnt, float* __restrict__ part_psum) {
  __shared__ float g[NEXP][DMODEL];
  __shared__ int s_cnt[NEXP];
  __shared__ float s_ps[NEXP];
  int tid = threadIdx.x;
  for (int i = tid; i < NEXP * DMODEL; i += 256) g[i >> 8][i & 255] = gate[i];
  if (tid < NEXP) { s_cnt[tid] = 0; s_ps[tid] = 0.f; }
  __syncthreads();
  int lane = tid & 63, wv = tid >> 6;
  float psacc[NEXP] = {0.f,0.f,0.f,0.f,0.f,0.f,0.f,0.f};
  for (int k = 0; k < 4; ++k) {
    int t = (blockIdx.x << 4) + (wv << 2) + k;  // 16 tokens/block, 4 per wave
    const float* xr = x + (size_t)t * DMODEL;
    float4 x4 = *(const float4*)(xr + 4 * lane);
    ushort4 u4;
    u4.x = f2bf(x4.x); u4.y = f2bf(x4.y); u4.z = f2bf(x4.z); u4.w = f2bf(x4.w);
    *(ushort4*)(xb + (size_t)t * DMODEL + 4 * lane) = u4;
    double l[NEXP];
#pragma unroll
    for (int e = 0; e < NEXP; ++e) {
      const float4 g4 = *(const float4*)&g[e][4 * lane];
      l[e] = (double)x4.x * (double)g4.x + (double)x4.y * (double)g4.y +
             (double)x4.z * (double)g4.z + (double)x4.w * (double)g4.w;
    }
#pragma unroll
    for (int e = 0; e < NEXP; ++e) {
#pragma unroll
      for (int d = 32; d; d >>= 1) l[e] += __shfl_xor(l[e], d);
    }
    // top-2 on exact logits, first-index tie-break (matches lax.top_k stability)
    int i1 = 0;
#pragma unroll
    for (int e = 1; e < NEXP; ++e) if (l[e] > l[i1]) i1 = e;
    int i2 = (i1 == 0) ? 1 : 0;
#pragma unroll
    for (int e = 0; e < NEXP; ++e) if (e != i1 && l[e] > l[i2]) i2 = e;
    double m = l[0];
#pragma unroll
    for (int e = 1; e < NEXP; ++e) m = (l[e] > m) ? l[e] : m;
    float pe[NEXP]; float s = 0.f;
#pragma unroll
    for (int e = 0; e < NEXP; ++e) { pe[e] = __expf((float)(l[e] - m)); s += pe[e]; }
    float inv = 1.f / s;
    float p1 = pe[i1] * inv, p2 = pe[i2] * inv;
    float wn = 1.f / (p1 + p2);
    if (lane == 0) {
      pack[t] = i1 | (i2 << 8);
      tkw[t] = make_float2(p1 * wn, p2 * wn);
      atomicAdd(&s_cnt[i1], 1); atomicAdd(&s_cnt[i2], 1);
#pragma unroll
      for (int e = 0; e < NEXP; ++e) psacc[e] += pe[e] * inv;
    }
  }
  if (lane == 0) {
#pragma unroll
    for (int e = 0; e < NEXP; ++e) atomicAdd(&s_ps[e], psacc[e]);
  }
  __syncthreads();
  if (tid < NEXP) {
    part_cnt[blockIdx.x * NEXP + tid] = s_cnt[tid];
    part_psum[blockIdx.x * NEXP + tid] = s_ps[tid];
  }
}

// ---------------- scan: per-block offsets, totals, aux loss ----------------
__global__ __launch_bounds__(512) void k_scan(
    const int* __restrict__ part_cnt, const float* __restrict__ part_psum,
    int* __restrict__ block_off, int* __restrict__ cnt_total, float* __restrict__ out) {
  __shared__ float s_ps[NEXP];
  __shared__ int s_ct[NEXP];
  int lane = threadIdx.x & 63, wv = threadIdx.x >> 6;  // wv = expert
  int base = lane * 128;                               // 8192 blocks / 64 lanes
  int lsum = 0; float ps = 0.f;
#pragma unroll 8
  for (int j = 0; j < 128; ++j) {
    lsum += part_cnt[(base + j) * NEXP + wv];
    ps += part_psum[(base + j) * NEXP + wv];
  }
  int incl = lsum;
#pragma unroll
  for (int d = 1; d < 64; d <<= 1) { int t = __shfl_up(incl, d); if (lane >= d) incl += t; }
  int run = incl - lsum;
#pragma unroll 8
  for (int j = 0; j < 128; ++j) {
    int v = part_cnt[(base + j) * NEXP + wv];
    block_off[(base + j) * NEXP + wv] = run;
    run += v;
  }
#pragma unroll
  for (int d = 32; d; d >>= 1) ps += __shfl_xor(ps, d);
  int total = __shfl(incl, 63);
  if (lane == 0) { cnt_total[wv] = total; s_ct[wv] = total; s_ps[wv] = ps; }
  __syncthreads();
  if (threadIdx.x == 0) {
    double aux = 0.0;
    for (int e = 0; e < NEXP; ++e)
      aux += ((double)s_ct[e] / 131072.0) * ((double)s_ps[e] / 131072.0);
    out[33554432] = (float)(8.0 * aux);
  }
}

// ---------------- scatter tokens into per-expert lists ----------------
__global__ void k_scatter(const int* __restrict__ pack, const float2* __restrict__ tkw,
                          const int* __restrict__ block_off, int* __restrict__ tok_list,
                          float* __restrict__ wt_list) {
  __shared__ int s_loc[NEXP];
  int tid = threadIdx.x;
  if (tid < NEXP) s_loc[tid] = 0;
  __syncthreads();
  if (tid < 16) {
    int t = (blockIdx.x << 4) + tid;
    int p = pack[t];
    float2 wv = tkw[t];
    int e1 = p & 255, e2 = (p >> 8) & 255;
    int o1 = block_off[blockIdx.x * NEXP + e1];
    int p1 = atomicAdd(&s_loc[e1], 1);
    tok_list[e1 * T_TOK + o1 + p1] = t;
    wt_list[e1 * T_TOK + o1 + p1] = wv.x;
    int o2 = block_off[blockIdx.x * NEXP + e2];
    int p2 = atomicAdd(&s_loc[e2], 1);
    tok_list[e2 * T_TOK + o2 + p2] = t;
    wt_list[e2 * T_TOK + o2 + p2] = wv.y;
  }
}

// ---------------- fused expert FFN: fc1 + silu + fc2, 64 tokens/block ----------------
__global__ __launch_bounds__(512, 2) void k_ffn(
    const unsigned short* __restrict__ xb, const unsigned short* __restrict__ w1b,
    const unsigned short* __restrict__ w2b, const float* __restrict__ b1,
    const float* __restrict__ b2, const int* __restrict__ tok_list,
    const float* __restrict__ wt_list, const int* __restrict__ cnt_total,
    float* __restrict__ out) {
  __shared__ unsigned short Xlds[64 * 264];  // stride 264 (=256+8) -> 16B aligned, low-conflict
  __shared__ unsigned short Hlds[64 * 136];  // 128-wide hidden chunk, stride 136
  __shared__ int s_tok[64];
  __shared__ float s_w[64];

  int bid = blockIdx.x;
  int e = -1, bi = 0, cum = 0;
#pragma unroll
  for (int ee = 0; ee < NEXP; ++ee) {
    int nb = (cnt_total[ee] + 63) >> 6;
    if (e < 0 && bid < cum + nb) { e = ee; bi = bid - cum; }
    cum += nb;
  }
  if (e < 0) return;
  int cnt = cnt_total[e];
  int nv = cnt - (bi << 6); if (nv > 64) nv = 64;

  int tid = threadIdx.x;
  if (tid < 64) {
    int basei = e * T_TOK + (bi << 6);
    int idx = basei + (tid < nv ? tid : 0);  // clamp: never read unwritten slots
    s_tok[tid] = tok_list[idx];
    s_w[tid] = (tid < nv) ? wt_list[idx] : 0.f;
  }
  __syncthreads();

  int lane = tid & 63, w = tid >> 6;
  int l15 = lane & 15, lg = lane >> 4;
  int tm = w >> 2, nq = w & 3;  // 2 token-halves x 4 column-quarters

  // stage gathered X rows (8 per wave) into LDS
  {
    int col8 = (lane & 31) * 8;
#pragma unroll
    for (int i = 0; i < 4; ++i) {
      int row = (w << 3) + (i << 1) + (lane >> 5);
      int tok = s_tok[row];
      short8 v = *(const short8*)(xb + (size_t)tok * DMODEL + col8);
      *(short8*)&Xlds[row * 264 + col8] = v;
    }
  }
  __syncthreads();

  // X fragments -> registers (reused across all 4 hidden chunks)
  short8 xfrag[2][8];
#pragma unroll
  for (int mt = 0; mt < 2; ++mt) {
    int row = tm * 32 + mt * 16 + l15;
#pragma unroll
    for (int ks = 0; ks < 8; ++ks)
      xfrag[mt][ks] = *(const short8*)&Xlds[row * 264 + ks * 32 + lg * 8];
  }

  f32x4 yacc[2][4];
#pragma unroll
  for (int mt = 0; mt < 2; ++mt)
#pragma unroll
    for (int nt = 0; nt < 4; ++nt) yacc[mt][nt] = (f32x4){0.f, 0.f, 0.f, 0.f};

  const unsigned short* w1e = w1b + (size_t)e * DHID * DMODEL;
  const unsigned short* w2e = w2b + (size_t)e * DMODEL * DHID;

  for (int c = 0; c < 4; ++c) {  // hidden chunks of 128
    f32x4 hacc[2][2];
#pragma unroll
    for (int mt = 0; mt < 2; ++mt)
#pragma unroll
      for (int nt = 0; nt < 2; ++nt) hacc[mt][nt] = (f32x4){0.f, 0.f, 0.f, 0.f};
    // GEMM1: H[64,128-chunk] = X[64,256] @ W1^T
#pragma unroll
    for (int ks = 0; ks < 8; ++ks) {
      int kk = ks * 32 + lg * 8;
      short8 bf0 = *(const short8*)(w1e + (size_t)(c * 128 + nq * 32 + l15) * DMODEL + kk);
      short8 bf1 = *(const short8*)(w1e + (size_t)(c * 128 + nq * 32 + 16 + l15) * DMODEL + kk);
#pragma unroll
      for (int mt = 0; mt < 2; ++mt) {
        hacc[mt][0] = __builtin_amdgcn_mfma_f32_16x16x32_bf16(xfrag[mt][ks], bf0, hacc[mt][0], 0, 0, 0);
        hacc[mt][1] = __builtin_amdgcn_mfma_f32_16x16x32_bf16(xfrag[mt][ks], bf1, hacc[mt][1], 0, 0, 0);
      }
    }
    // bias + silu -> bf16 -> LDS
#pragma unroll
    for (int nt = 0; nt < 2; ++nt) {
      int hcol = nq * 32 + nt * 16 + l15;
      float b1v = b1[e * DHID + c * 128 + hcol];
#pragma unroll
      for (int mt = 0; mt < 2; ++mt) {
#pragma unroll
        for (int r = 0; r < 4; ++r) {
          float z = hacc[mt][nt][r] + b1v;
          float sv = z / (1.f + __expf(-z));
          Hlds[(tm * 32 + mt * 16 + lg * 4 + r) * 136 + hcol] = f2bf(sv);
        }
      }
    }
    __syncthreads();
    // GEMM2 partial: Y[64,256] += H_chunk @ W2^T(chunk)
#pragma unroll
    for (int ks = 0; ks < 4; ++ks) {
      int kk = ks * 32 + lg * 8;
      short8 a0 = *(const short8*)&Hlds[(tm * 32 + l15) * 136 + kk];
      short8 a1 = *(const short8*)&Hlds[(tm * 32 + 16 + l15) * 136 + kk];
#pragma unroll
      for (int nt = 0; nt < 4; ++nt) {
        int d = nq * 64 + nt * 16 + l15;
        short8 bf = *(const short8*)(w2e + (size_t)d * DHID + c * 128 + kk);
        yacc[0][nt] = __builtin_amdgcn_mfma_f32_16x16x32_bf16(a0, bf, yacc[0][nt], 0, 0, 0);
        yacc[1][nt] = __builtin_amdgcn_mfma_f32_16x16x32_bf16(a1, bf, yacc[1][nt], 0, 0, 0);
      }
    }
    __syncthreads();
  }

  // epilogue: out += w * (Y + b2), exactly 2 contributions per token
#pragma unroll
  for (int nt = 0; nt < 4; ++nt) {
    int d = nq * 64 + nt * 16 + l15;
    float b2v = b2[e * DMODEL + d];
#pragma unroll
    for (int mt = 0; mt < 2; ++mt) {
#pragma unroll
      for (int r = 0; r < 4; ++r) {
        int row = tm * 32 + mt * 16 + lg * 4 + r;
        if (row < nv) {
          float val = s_w[row] * (yacc[mt][nt][r] + b2v);
          atomicAdd(out + (size_t)s_tok[row] * DMODEL + d, val);
        }
      }
    }
  }
}

extern "C" void kernel_launch(void* const* d_in, const int* in_sizes, int n_in,
                              void* d_out, int out_size, void* d_ws, size_t ws_size,
                              hipStream_t stream) {
  const float* x    = (const float*)d_in[0];
  const float* gate = (const float*)d_in[1];
  const float* w1   = (const float*)d_in[2];
  const float* b1   = (const float*)d_in[3];
  const float* w2   = (const float*)d_in[4];
  const float* b2   = (const float*)d_in[5];
  float* out = (float*)d_out;
  char* ws = (char*)d_ws;

  unsigned short* xb  = (unsigned short*)(ws);
  unsigned short* w1b = (unsigned short*)(ws + 67108864);
  unsigned short* w2b = (unsigned short*)(ws + 69206016);
  int*    tok_list  = (int*)(ws + 71303168);
  float*  wt_list   = (float*)(ws + 75497472);
  int*    pack      = (int*)(ws + 79691776);
  float2* tkw       = (float2*)(ws + 80216064);
  int*    part_cnt  = (int*)(ws + 81264640);
  float*  part_psum = (float*)(ws + 81526784);
  int*    block_off = (int*)(ws + 81788928);
  int*    cnt_total = (int*)(ws + 82051072);

  hipMemsetAsync(d_out, 0, (size_t)out_size * 4, stream);
  k_wconv<<<1024, 256, 0, stream>>>(w1, w2, w1b, w2b);
  k_router<<<8192, 256, 0, stream>>>(x, gate, xb, pack, tkw, part_cnt, part_psum);
  k_scan<<<1, 512, 0, stream>>>(part_cnt, part_psum, block_off, cnt_total, out);
  k_scatter<<<8192, 64, 0, stream>>>(pack, tkw, block_off, tok_list, wt_list);
  k_ffn<<<4103, 512, 0, stream>>>(xb, w1b, w2b, b1, b2, tok_list, wt_list, cnt_total, out);
}

// Round 2
// 788.698 us; speedup vs baseline: 1.4498x; 1.4498x over previous
//
#include <hip/hip_runtime.h>

typedef __attribute__((ext_vector_type(8))) short short8;
typedef __attribute__((ext_vector_type(4))) float f32x4;

#define T_TOK  131072
#define DMODEL 256
#define DHID   512
#define NEXP   8

// ---------------- ws layout (bytes) ----------------
// xb        : 0          size 67108864   (T*256 bf16)
// w1b       : 67108864   size 2097152
// w2b       : 69206016   size 2097152
// tok_list  : 71303168   size 4194304    (E*T int)
// wt_list   : 75497472   size 4194304    (E*T float)
// pack      : 79691776   size 524288     (T int)
// tkw       : 80216064   size 1048576    (T float2)
// part_cnt  : 81264640   size 262144     (8192*8 int)
// part_psum : 81526784   size 262144
// block_off : 81788928   size 262144
// cnt_total : 82051072   size 32

__device__ __forceinline__ unsigned short f2bf(float f) {
  unsigned int u = __float_as_uint(f);
  u = (u + 0x7FFFu + ((u >> 16) & 1u)) >> 16;
  return (unsigned short)u;
}

// async 16B global->LDS; LDS dest is wave-uniform base (+lane*16 by HW),
// global src is per-lane.
__device__ __forceinline__ void gload16(const void* g, void* l) {
  __builtin_amdgcn_global_load_lds(
      (const __attribute__((address_space(1))) void*)g,
      (__attribute__((address_space(3))) void*)l, 16, 0, 0);
}

// ---------------- weight fp32 -> bf16 ----------------
__global__ void k_wconv(const float* __restrict__ w1, const float* __restrict__ w2,
                        unsigned short* __restrict__ w1b, unsigned short* __restrict__ w2b) {
  int i = blockIdx.x * 256 + threadIdx.x;
  float4 a = ((const float4*)w1)[i];
  ushort4 ua; ua.x = f2bf(a.x); ua.y = f2bf(a.y); ua.z = f2bf(a.z); ua.w = f2bf(a.w);
  ((ushort4*)w1b)[i] = ua;
  float4 b = ((const float4*)w2)[i];
  ushort4 ub; ub.x = f2bf(b.x); ub.y = f2bf(b.y); ub.z = f2bf(b.z); ub.w = f2bf(b.w);
  ((ushort4*)w2b)[i] = ub;
}

// ---------------- router: fp64 logits, top-2, x->bf16, per-block hist ----------------
__global__ __launch_bounds__(256) void k_router(
    const float* __restrict__ x, const float* __restrict__ gate,
    unsigned short* __restrict__ xb, int* __restrict__ pack, float2* __restrict__ tkw,
    int* __restrict__ part_cnt, float* __restrict__ part_psum) {
  __shared__ float g[NEXP][DMODEL];
  __shared__ int s_cnt[NEXP];
  __shared__ float s_ps[NEXP];
  int tid = threadIdx.x;
  for (int i = tid; i < NEXP * DMODEL; i += 256) g[i >> 8][i & 255] = gate[i];
  if (tid < NEXP) { s_cnt[tid] = 0; s_ps[tid] = 0.f; }
  __syncthreads();
  int lane = tid & 63, wv = tid >> 6;
  float psacc[NEXP] = {0.f,0.f,0.f,0.f,0.f,0.f,0.f,0.f};
  for (int k = 0; k < 4; ++k) {
    int t = (blockIdx.x << 4) + (wv << 2) + k;
    const float* xr = x + (size_t)t * DMODEL;
    float4 x4 = *(const float4*)(xr + 4 * lane);
    ushort4 u4;
    u4.x = f2bf(x4.x); u4.y = f2bf(x4.y); u4.z = f2bf(x4.z); u4.w = f2bf(x4.w);
    *(ushort4*)(xb + (size_t)t * DMODEL + 4 * lane) = u4;
    double l[NEXP];
#pragma unroll
    for (int e = 0; e < NEXP; ++e) {
      const float4 g4 = *(const float4*)&g[e][4 * lane];
      l[e] = (double)x4.x * (double)g4.x + (double)x4.y * (double)g4.y +
             (double)x4.z * (double)g4.z + (double)x4.w * (double)g4.w;
    }
#pragma unroll
    for (int e = 0; e < NEXP; ++e) {
#pragma unroll
      for (int d = 32; d; d >>= 1) l[e] += __shfl_xor(l[e], d);
    }
    int i1 = 0;
#pragma unroll
    for (int e = 1; e < NEXP; ++e) if (l[e] > l[i1]) i1 = e;
    int i2 = (i1 == 0) ? 1 : 0;
#pragma unroll
    for (int e = 0; e < NEXP; ++e) if (e != i1 && l[e] > l[i2]) i2 = e;
    double m = l[0];
#pragma unroll
    for (int e = 1; e < NEXP; ++e) m = (l[e] > m) ? l[e] : m;
    float pe[NEXP]; float s = 0.f;
#pragma unroll
    for (int e = 0; e < NEXP; ++e) { pe[e] = __expf((float)(l[e] - m)); s += pe[e]; }
    float inv = 1.f / s;
    float p1 = pe[i1] * inv, p2 = pe[i2] * inv;
    float wn = 1.f / (p1 + p2);
    if (lane == 0) {
      pack[t] = i1 | (i2 << 8);
      tkw[t] = make_float2(p1 * wn, p2 * wn);
      atomicAdd(&s_cnt[i1], 1); atomicAdd(&s_cnt[i2], 1);
#pragma unroll
      for (int e = 0; e < NEXP; ++e) psacc[e] += pe[e] * inv;
    }
  }
  if (lane == 0) {
#pragma unroll
    for (int e = 0; e < NEXP; ++e) atomicAdd(&s_ps[e], psacc[e]);
  }
  __syncthreads();
  if (tid < NEXP) {
    part_cnt[blockIdx.x * NEXP + tid] = s_cnt[tid];
    part_psum[blockIdx.x * NEXP + tid] = s_ps[tid];
  }
}

// ---------------- scan: per-block offsets, totals, aux loss ----------------
__global__ __launch_bounds__(512) void k_scan(
    const int* __restrict__ part_cnt, const float* __restrict__ part_psum,
    int* __restrict__ block_off, int* __restrict__ cnt_total, float* __restrict__ out) {
  __shared__ float s_ps[NEXP];
  __shared__ int s_ct[NEXP];
  int lane = threadIdx.x & 63, wv = threadIdx.x >> 6;
  int base = lane * 128;
  int lsum = 0; float ps = 0.f;
#pragma unroll 8
  for (int j = 0; j < 128; ++j) {
    lsum += part_cnt[(base + j) * NEXP + wv];
    ps += part_psum[(base + j) * NEXP + wv];
  }
  int incl = lsum;
#pragma unroll
  for (int d = 1; d < 64; d <<= 1) { int t = __shfl_up(incl, d); if (lane >= d) incl += t; }
  int run = incl - lsum;
#pragma unroll 8
  for (int j = 0; j < 128; ++j) {
    int v = part_cnt[(base + j) * NEXP + wv];
    block_off[(base + j) * NEXP + wv] = run;
    run += v;
  }
#pragma unroll
  for (int d = 32; d; d >>= 1) ps += __shfl_xor(ps, d);
  int total = __shfl(incl, 63);
  if (lane == 0) { cnt_total[wv] = total; s_ct[wv] = total; s_ps[wv] = ps; }
  __syncthreads();
  if (threadIdx.x == 0) {
    double aux = 0.0;
    for (int e = 0; e < NEXP; ++e)
      aux += ((double)s_ct[e] / 131072.0) * ((double)s_ps[e] / 131072.0);
    out[33554432] = (float)(8.0 * aux);
  }
}

// ---------------- scatter tokens into per-expert lists ----------------
__global__ void k_scatter(const int* __restrict__ pack, const float2* __restrict__ tkw,
                          const int* __restrict__ block_off, int* __restrict__ tok_list,
                          float* __restrict__ wt_list) {
  __shared__ int s_loc[NEXP];
  int tid = threadIdx.x;
  if (tid < NEXP) s_loc[tid] = 0;
  __syncthreads();
  if (tid < 16) {
    int t = (blockIdx.x << 4) + tid;
    int p = pack[t];
    float2 wv = tkw[t];
    int e1 = p & 255, e2 = (p >> 8) & 255;
    int o1 = block_off[blockIdx.x * NEXP + e1];
    int p1 = atomicAdd(&s_loc[e1], 1);
    tok_list[e1 * T_TOK + o1 + p1] = t;
    wt_list[e1 * T_TOK + o1 + p1] = wv.x;
    int o2 = block_off[blockIdx.x * NEXP + e2];
    int p2 = atomicAdd(&s_loc[e2], 1);
    tok_list[e2 * T_TOK + o2 + p2] = t;
    wt_list[e2 * T_TOK + o2 + p2] = wv.y;
  }
}

// ---------------- fused expert FFN with async LDS-staged weights ----------------
// 64 tokens/block, 8 waves (2 token-halves x 4 col-quarters), hidden chunk = 64.
// All staged tiles: linear LDS dest via global_load_lds + XOR-swizzled (slot^=row&7)
// global source; reads apply the same XOR -> conflict-free ds_read_b128.
__global__ __launch_bounds__(512, 2) void k_ffn(
    const unsigned short* __restrict__ xb, const unsigned short* __restrict__ w1b,
    const unsigned short* __restrict__ w2b, const float* __restrict__ b1,
    const float* __restrict__ b2, const int* __restrict__ tok_list,
    const float* __restrict__ wt_list, const int* __restrict__ cnt_total,
    float* __restrict__ out) {
  __shared__ __align__(16) unsigned short X[64 * 256];    // 64 rows x 32 slots, 32KB
  __shared__ __align__(16) unsigned short W1s[64 * 256];  // 64 hid rows x 32 slots, 32KB
  __shared__ __align__(16) unsigned short W2s[256 * 64];  // 256 out rows x 8 slots, 32KB
  __shared__ __align__(16) unsigned short H[64 * 72];     // padded stride 72
  __shared__ int s_tok[64];
  __shared__ float s_w[64];

  int bid = blockIdx.x;
  int e = -1, bi = 0, cum = 0;
#pragma unroll
  for (int ee = 0; ee < NEXP; ++ee) {
    int nb = (cnt_total[ee] + 63) >> 6;
    if (e < 0 && bid < cum + nb) { e = ee; bi = bid - cum; }
    cum += nb;
  }
  if (e < 0) return;
  int cnt = cnt_total[e];
  int nv = cnt - (bi << 6); if (nv > 64) nv = 64;

  int tid = threadIdx.x;
  if (tid < 64) {
    int basei = e * T_TOK + (bi << 6);
    int idx = basei + (tid < nv ? tid : 0);
    s_tok[tid] = tok_list[idx];
    s_w[tid] = (tid < nv) ? wt_list[idx] : 0.f;
  }
  __syncthreads();

  int lane = tid & 63, w = tid >> 6;
  int l15 = lane & 15, lg = lane >> 4;
  int tm = w >> 2, nq = w & 3;

  const unsigned short* w1e = w1b + (size_t)e * DHID * DMODEL;
  const unsigned short* w2e = w2b + (size_t)e * DMODEL * DHID;

  // stage X (gathered rows; per-lane swizzled source, linear dest)
#pragma unroll
  for (int i = 0; i < 4; ++i) {
    int t = i * 512 + w * 64 + lane;
    int row = t >> 5, c = t & 31;
    const unsigned short* src = xb + (size_t)s_tok[row] * DMODEL + (size_t)((c ^ (row & 7)) << 3);
    gload16(src, &X[(size_t)(i * 512 + w * 64) * 8]);
  }
  // stage W1 chunk 0
#pragma unroll
  for (int i = 0; i < 4; ++i) {
    int t = i * 512 + w * 64 + lane;
    int row = t >> 5, c = t & 31;
    const unsigned short* src = w1e + (size_t)row * DMODEL + (size_t)((c ^ (row & 7)) << 3);
    gload16(src, &W1s[(size_t)(i * 512 + w * 64) * 8]);
  }
  __syncthreads();  // implicit vmcnt(0): X + W1(0) landed

  // X fragments -> registers (held across all 8 phases)
  short8 xfrag[2][8];
#pragma unroll
  for (int mt = 0; mt < 2; ++mt) {
    int row = tm * 32 + mt * 16 + l15;
    int r7 = row & 7;
#pragma unroll
    for (int ks = 0; ks < 8; ++ks)
      xfrag[mt][ks] = *(const short8*)&X[(size_t)(row * 32 + (((ks << 2) | lg) ^ r7)) << 3];
  }

  // issue W2 chunk 0 (flies over GEMM1 of phase 0)
#pragma unroll
  for (int i = 0; i < 4; ++i) {
    int t = i * 512 + w * 64 + lane;
    int row = t >> 3, c = t & 7;
    const unsigned short* src = w2e + (size_t)row * DHID + (size_t)((c ^ (row & 7)) << 3);
    gload16(src, &W2s[(size_t)(i * 512 + w * 64) * 8]);
  }

  float b1v[8];
#pragma unroll
  for (int cc = 0; cc < 8; ++cc) b1v[cc] = b1[e * DHID + cc * 64 + nq * 16 + l15];

  f32x4 yacc[2][4];
#pragma unroll
  for (int mt = 0; mt < 2; ++mt)
#pragma unroll
    for (int nt = 0; nt < 4; ++nt) yacc[mt][nt] = (f32x4){0.f, 0.f, 0.f, 0.f};

  int br = nq * 16 + l15;     // W1 local row for this wave
  int br7 = br & 7;

  for (int cc = 0; cc < 8; ++cc) {
    // ---- GEMM1: H_chunk[64 x 64] = X @ W1c^T (W1s ready; W2 staging in flight) ----
    f32x4 hacc[2];
    hacc[0] = (f32x4){0.f, 0.f, 0.f, 0.f};
    hacc[1] = (f32x4){0.f, 0.f, 0.f, 0.f};
#pragma unroll
    for (int ks = 0; ks < 8; ++ks) {
      short8 bf = *(const short8*)&W1s[(size_t)(br * 32 + (((ks << 2) | lg) ^ br7)) << 3];
      hacc[0] = __builtin_amdgcn_mfma_f32_16x16x32_bf16(xfrag[0][ks], bf, hacc[0], 0, 0, 0);
      hacc[1] = __builtin_amdgcn_mfma_f32_16x16x32_bf16(xfrag[1][ks], bf, hacc[1], 0, 0, 0);
    }
    // bias + silu -> H (prev phase's H readers finished at loop-end barrier)
#pragma unroll
    for (int mt = 0; mt < 2; ++mt)
#pragma unroll
      for (int r = 0; r < 4; ++r) {
        float z = hacc[mt][r] + b1v[cc];
        float sv = z / (1.f + __expf(-z));
        H[(tm * 32 + mt * 16 + lg * 4 + r) * 72 + nq * 16 + l15] = f2bf(sv);
      }
    __syncthreads();  // drains W2(cc); H visible; W1s reads done

    // issue W1(cc+1) -> flies over GEMM2
    if (cc < 7) {
#pragma unroll
      for (int i = 0; i < 4; ++i) {
        int t = i * 512 + w * 64 + lane;
        int row = t >> 5, c = t & 31;
        const unsigned short* src =
            w1e + (size_t)((cc + 1) * 64 + row) * DMODEL + (size_t)((c ^ (row & 7)) << 3);
        gload16(src, &W1s[(size_t)(i * 512 + w * 64) * 8]);
      }
    }

    // ---- GEMM2: yacc += H_chunk @ W2c^T ----
#pragma unroll
    for (int ks = 0; ks < 2; ++ks) {
      short8 a0 = *(const short8*)&H[(tm * 32 + l15) * 72 + ks * 32 + lg * 8];
      short8 a1 = *(const short8*)&H[(tm * 32 + 16 + l15) * 72 + ks * 32 + lg * 8];
#pragma unroll
      for (int nt = 0; nt < 4; ++nt) {
        int dr = nq * 64 + nt * 16 + l15;
        short8 bf = *(const short8*)&W2s[(size_t)(dr * 8 + ((((ks << 2) | lg)) ^ (dr & 7))) << 3];
        yacc[0][nt] = __builtin_amdgcn_mfma_f32_16x16x32_bf16(a0, bf, yacc[0][nt], 0, 0, 0);
        yacc[1][nt] = __builtin_amdgcn_mfma_f32_16x16x32_bf16(a1, bf, yacc[1][nt], 0, 0, 0);
      }
    }
    __syncthreads();  // drains W1(cc+1); W2s + H reads done

    // issue W2(cc+1) -> flies over next GEMM1
    if (cc < 7) {
#pragma unroll
      for (int i = 0; i < 4; ++i) {
        int t = i * 512 + w * 64 + lane;
        int row = t >> 3, c = t & 7;
        const unsigned short* src =
            w2e + (size_t)row * DHID + (size_t)((cc + 1) * 64) + (size_t)((c ^ (row & 7)) << 3);
        gload16(src, &W2s[(size_t)(i * 512 + w * 64) * 8]);
      }
    }
  }

  // epilogue: out += w * (Y + b2), exactly 2 contributions per token element
#pragma unroll
  for (int nt = 0; nt < 4; ++nt) {
    int d = nq * 64 + nt * 16 + l15;
    float b2v = b2[e * DMODEL + d];
#pragma unroll
    for (int mt = 0; mt < 2; ++mt) {
#pragma unroll
      for (int r = 0; r < 4; ++r) {
        int row = tm * 32 + mt * 16 + lg * 4 + r;
        if (row < nv) {
          float val = s_w[row] * (yacc[mt][nt][r] + b2v);
          atomicAdd(out + (size_t)s_tok[row] * DMODEL + d, val);
        }
      }
    }
  }
}

extern "C" void kernel_launch(void* const* d_in, const int* in_sizes, int n_in,
                              void* d_out, int out_size, void* d_ws, size_t ws_size,
                              hipStream_t stream) {
  const float* x    = (const float*)d_in[0];
  const float* gate = (const float*)d_in[1];
  const float* w1   = (const float*)d_in[2];
  const float* b1   = (const float*)d_in[3];
  const float* w2   = (const float*)d_in[4];
  const float* b2   = (const float*)d_in[5];
  float* out = (float*)d_out;
  char* ws = (char*)d_ws;

  unsigned short* xb  = (unsigned short*)(ws);
  unsigned short* w1b = (unsigned short*)(ws + 67108864);
  unsigned short* w2b = (unsigned short*)(ws + 69206016);
  int*    tok_list  = (int*)(ws + 71303168);
  float*  wt_list   = (float*)(ws + 75497472);
  int*    pack      = (int*)(ws + 79691776);
  float2* tkw       = (float2*)(ws + 80216064);
  int*    part_cnt  = (int*)(ws + 81264640);
  float*  part_psum = (float*)(ws + 81526784);
  int*    block_off = (int*)(ws + 81788928);
  int*    cnt_total = (int*)(ws + 82051072);

  hipMemsetAsync(d_out, 0, (size_t)out_size * 4, stream);
  k_wconv<<<1024, 256, 0, stream>>>(w1, w2, w1b, w2b);
  k_router<<<8192, 256, 0, stream>>>(x, gate, xb, pack, tkw, part_cnt, part_psum);
  k_scan<<<1, 512, 0, stream>>>(part_cnt, part_psum, block_off, cnt_total, out);
  k_scatter<<<8192, 64, 0, stream>>>(pack, tkw, block_off, tok_list, wt_list);
  k_ffn<<<4103, 512, 0, stream>>>(xb, w1b, w2b, b1, b2, tok_list, wt_list, cnt_total, out);
}